// Round 1
// baseline (2243.037 us; speedup 1.0000x reference)
//
#include <hip/hip_runtime.h>

#define NB 4096      // N = H*W
#define BATCH 4
#define CD 256       // channels
#define ED 64        // embedding dim
#define KNN 24
#define TEN_BITS 0x41200000u  // __float_as_uint(10.0f)

// ---------------- K1: emb[b,n,e] = sum_c x[b,c,n]*dist_w[e,c];  sq[b,n] = sum_e emb^2
__global__ __launch_bounds__(256) void k_emb(const float* __restrict__ x,
                                             const float* __restrict__ dist_w,
                                             float* __restrict__ emb,
                                             float* __restrict__ sq) {
  __shared__ float wds[ED * CD];   // 64 KB
  __shared__ float red[64 * 4];
  const int b = blockIdx.x >> 6;
  const int n0 = (blockIdx.x & 63) << 6;
  const int tid = threadIdx.x;
  const float4* wsrc = (const float4*)dist_w;
  float4* wdst = (float4*)wds;
#pragma unroll
  for (int k = 0; k < 16; ++k) wdst[tid + 256 * k] = wsrc[tid + 256 * k];
  __syncthreads();
  const int eg = tid >> 6;   // 0..3
  const int nl = tid & 63;
  const int n = n0 + nl;
  float acc[16];
#pragma unroll
  for (int t = 0; t < 16; ++t) acc[t] = 0.f;
  const float* xb = x + (size_t)b * CD * NB + n;
#pragma unroll 4
  for (int c = 0; c < CD; ++c) {
    float xv = xb[(size_t)c * NB];
#pragma unroll
    for (int t = 0; t < 16; ++t)
      acc[t] = fmaf(xv, wds[(eg * 16 + t) * CD + c], acc[t]);
  }
  float s = 0.f;
#pragma unroll
  for (int t = 0; t < 16; ++t) s = fmaf(acc[t], acc[t], s);
  float* ebase = emb + ((size_t)(b * NB + n)) * ED + eg * 16;
#pragma unroll
  for (int t4 = 0; t4 < 4; ++t4)
    ((float4*)ebase)[t4] = make_float4(acc[4 * t4], acc[4 * t4 + 1], acc[4 * t4 + 2], acc[4 * t4 + 3]);
  red[nl * 4 + eg] = s;
  __syncthreads();
  if (tid < 64)
    sq[b * NB + n0 + tid] = red[tid * 4] + red[tid * 4 + 1] + red[tid * 4 + 2] + red[tid * 4 + 3];
}

// ---------------- K2: X_lin[b,n,c] = sum_k x[b,k,n]*fc_w[c,k] + fc_b[c]
__global__ __launch_bounds__(256) void k_xlin(const float* __restrict__ x,
                                              const float* __restrict__ fc_w,
                                              const float* __restrict__ fc_b,
                                              float* __restrict__ xlin) {
  __shared__ float xt[64 * 64];     // [k][n]
  __shared__ float wt[64 * 260];    // [k][c] padded
  const int b = blockIdx.x >> 6;
  const int n0 = (blockIdx.x & 63) << 6;
  const int tid = threadIdx.x;
  const int nl4 = tid & 15;   // n = 4*nl4 + i
  const int cg = tid >> 4;    // c = 4*cg + 64*j + l
  float acc[4][16];
#pragma unroll
  for (int i = 0; i < 4; ++i)
#pragma unroll
    for (int j = 0; j < 16; ++j) acc[i][j] = 0.f;

  for (int kt = 0; kt < 4; ++kt) {
    __syncthreads();
#pragma unroll 4
    for (int i = 0; i < 16; ++i) {
      int idx = tid + 256 * i;
      int k = idx >> 6, n = idx & 63;
      xt[idx] = x[((size_t)(b * CD + kt * 64 + k)) * NB + n0 + n];
    }
#pragma unroll 4
    for (int i = 0; i < 16; ++i) {
      int q = tid + 256 * i;
      int c = q >> 4, k4 = (q & 15) * 4;
      float4 v = *(const float4*)&fc_w[(size_t)c * CD + kt * 64 + k4];
      wt[(k4 + 0) * 260 + c] = v.x;
      wt[(k4 + 1) * 260 + c] = v.y;
      wt[(k4 + 2) * 260 + c] = v.z;
      wt[(k4 + 3) * 260 + c] = v.w;
    }
    __syncthreads();
#pragma unroll 2
    for (int k = 0; k < 64; ++k) {
      float4 xv = *(const float4*)&xt[k * 64 + 4 * nl4];
#pragma unroll
      for (int j = 0; j < 4; ++j) {
        float4 wv = *(const float4*)&wt[k * 260 + 4 * cg + 64 * j];
        const float* wp = &wv.x;
#pragma unroll
        for (int l = 0; l < 4; ++l) {
          acc[0][4 * j + l] = fmaf(xv.x, wp[l], acc[0][4 * j + l]);
          acc[1][4 * j + l] = fmaf(xv.y, wp[l], acc[1][4 * j + l]);
          acc[2][4 * j + l] = fmaf(xv.z, wp[l], acc[2][4 * j + l]);
          acc[3][4 * j + l] = fmaf(xv.w, wp[l], acc[3][4 * j + l]);
        }
      }
    }
  }
#pragma unroll
  for (int i = 0; i < 4; ++i) {
    int n = n0 + 4 * nl4 + i;
    float* dst = xlin + ((size_t)(b * NB + n)) * CD;
#pragma unroll
    for (int j = 0; j < 4; ++j) {
      int c = 4 * cg + 64 * j;
      float4 bv = *(const float4*)&fc_b[c];
      float4 o;
      o.x = acc[i][4 * j + 0] + bv.x;
      o.y = acc[i][4 * j + 1] + bv.y;
      o.z = acc[i][4 * j + 2] + bv.z;
      o.w = acc[i][4 * j + 3] + bv.w;
      *(float4*)&dst[c] = o;
    }
  }
}

// ---------------- K3: distances + exact top-24 (ties by index) + threshold; builds row lists, Dv, De counts
__global__ __launch_bounds__(256) void k_dist(const float* __restrict__ emb,
                                              const float* __restrict__ sq,
                                              int* __restrict__ row_idx,
                                              int* __restrict__ row_cnt,
                                              int* __restrict__ col_cnt) {
  __shared__ float eN[64 * 68];
  __shared__ float eM[128 * 68];
  __shared__ unsigned int d2t[64 * 129];
  __shared__ unsigned long long top[64 * 25];
  __shared__ float sqN[64];
  __shared__ float sqM[128];

  const int b = blockIdx.x >> 6;
  const int n0 = (blockIdx.x & 63) << 6;
  const int tid = threadIdx.x;
  const float* embB = emb + (size_t)b * NB * ED;

#pragma unroll
  for (int k = 0; k < 4; ++k) {
    int q = tid + 256 * k;
    int r = q >> 4, e4 = q & 15;
    *(float4*)&eN[r * 68 + e4 * 4] = *(const float4*)&embB[(size_t)(n0 + r) * ED + e4 * 4];
  }
  if (tid < 64) sqN[tid] = sq[b * NB + n0 + tid];
#pragma unroll
  for (int k = 0; k < 7; ++k) {
    int q = tid + 256 * k;
    if (q < 1600) top[q] = ~0ULL;
  }
  __syncthreads();

  const int rg = tid >> 4;  // 0..15
  const int mg = tid & 15;

  for (int ci = 0; ci < 32; ++ci) {
    const int m0 = ci << 7;
#pragma unroll
    for (int k = 0; k < 8; ++k) {
      int q = tid + 256 * k;
      int r = q >> 4, e4 = q & 15;
      *(float4*)&eM[r * 68 + e4 * 4] = *(const float4*)&embB[(size_t)(m0 + r) * ED + e4 * 4];
    }
    if (tid >= 128) sqM[tid - 128] = sq[b * NB + m0 + (tid - 128)];
    __syncthreads();

    float acc[4][8];
#pragma unroll
    for (int i = 0; i < 4; ++i)
#pragma unroll
      for (int j = 0; j < 8; ++j) acc[i][j] = 0.f;

#pragma unroll
    for (int e4 = 0; e4 < 16; ++e4) {
      float4 av[4], bv[8];
#pragma unroll
      for (int i = 0; i < 4; ++i) av[i] = *(const float4*)&eN[(rg + 16 * i) * 68 + e4 * 4];
#pragma unroll
      for (int j = 0; j < 8; ++j) bv[j] = *(const float4*)&eM[(mg + 16 * j) * 68 + e4 * 4];
#pragma unroll
      for (int i = 0; i < 4; ++i)
#pragma unroll
        for (int j = 0; j < 8; ++j) {
          acc[i][j] = fmaf(av[i].x, bv[j].x, acc[i][j]);
          acc[i][j] = fmaf(av[i].y, bv[j].y, acc[i][j]);
          acc[i][j] = fmaf(av[i].z, bv[j].z, acc[i][j]);
          acc[i][j] = fmaf(av[i].w, bv[j].w, acc[i][j]);
        }
    }
#pragma unroll
    for (int i = 0; i < 4; ++i) {
      int r = rg + 16 * i;
      float sn = sqN[r];
#pragma unroll
      for (int j = 0; j < 8; ++j) {
        int ml = mg + 16 * j;
        float d2 = sn + sqM[ml] - 2.f * acc[i][j];
        float dist = sqrtf(fmaxf(d2, 0.f));
        d2t[r * 129 + ml] = __float_as_uint(dist);
      }
    }
    __syncthreads();
    if (tid < 64) {
      const int r = tid;
      unsigned long long worst = top[r * 25 + 23];
#pragma unroll 4
      for (int jj = 0; jj < 128; ++jj) {
        unsigned long long p =
            ((unsigned long long)d2t[r * 129 + jj] << 32) | (unsigned int)(m0 + jj);
        if (p < worst) {
          int pos = 23;
          while (pos > 0 && top[r * 25 + pos - 1] > p) {
            top[r * 25 + pos] = top[r * 25 + pos - 1];
            --pos;
          }
          top[r * 25 + pos] = p;
          worst = top[r * 25 + 23];
        }
      }
    }
    // no barrier here: lanes 64..255 stage next eM (not read by drain); post-stage barrier orders all
  }
  if (tid < 64) {
    const int r = tid;
    const int n = n0 + r;
    int cnt = 0;
    const int base = (b * NB + n) * KNN;
    for (int j = 0; j < KNN; ++j) {
      unsigned long long p = top[r * 25 + j];
      unsigned int key = (unsigned int)(p >> 32);
      if (key <= TEN_BITS) {  // dist <= 10.0
        int m = (int)(p & 0xffffffffu);
        row_idx[base + cnt] = m;
        atomicAdd(&col_cnt[b * NB + m], 1);
        ++cnt;
      }
    }
    row_cnt[b * NB + n] = cnt;  // Dv (self always present -> cnt >= 1)
  }
}

// ---------------- K4: exclusive scan of col_cnt (16384 entries), 1 block
__global__ __launch_bounds__(256) void k_scan(const int* __restrict__ col_cnt,
                                              int* __restrict__ col_start,
                                              int* __restrict__ col_cursor) {
  __shared__ int part[256];
  const int tid = threadIdx.x;
  const int base = tid * 64;
  int s = 0;
  for (int j = 0; j < 64; ++j) s += col_cnt[base + j];
  part[tid] = s;
  __syncthreads();
  for (int off = 1; off < 256; off <<= 1) {
    int v = (tid >= off) ? part[tid - off] : 0;
    __syncthreads();
    part[tid] += v;
    __syncthreads();
  }
  int run = part[tid] - s;  // exclusive prefix of this chunk
  for (int j = 0; j < 64; ++j) {
    col_start[base + j] = run;
    col_cursor[base + j] = run;
    run += col_cnt[base + j];
  }
}

// ---------------- K5: fill CSC column lists
__global__ __launch_bounds__(256) void k_fill(const int* __restrict__ row_idx,
                                              const int* __restrict__ row_cnt,
                                              int* __restrict__ col_cursor,
                                              int* __restrict__ col_list) {
  const int row = blockIdx.x * 256 + threadIdx.x;  // b*NB+n
  const int b = row >> 12;
  const int n = row & 4095;
  const int cnt = row_cnt[row];
  for (int j = 0; j < cnt; ++j) {
    int m = row_idx[row * KNN + j];
    int pos = atomicAdd(&col_cursor[(b << 12) + m], 1);
    col_list[pos] = n;
  }
}

// ---------------- K6: Yd[e,c] = (sum_{m in col(e)} X_lin[m,c]) / De[e]
__global__ __launch_bounds__(256) void k_yd(const float* __restrict__ xlin,
                                            const int* __restrict__ col_cnt,
                                            const int* __restrict__ col_start,
                                            const int* __restrict__ col_list,
                                            float* __restrict__ yd) {
  const int be = blockIdx.x;  // b*NB + e
  const int b = be >> 12;
  const int c = threadIdx.x;
  const int deg = col_cnt[be];
  const int start = col_start[be];
  float acc = 0.f;
  for (int j = 0; j < deg; ++j) {
    int m = col_list[start + j];
    acc += xlin[(((size_t)(b << 12) + m) << 8) + c];
  }
  yd[((size_t)be << 8) + c] = acc / (float)deg;
}

// ---------------- K7: out_flat[n,c] = sum_{e in row(n)} Yd[e,c]/Dv[n] + x[b,c,n]; accumulate BN sums
__global__ __launch_bounds__(256) void k_out(const float* __restrict__ yd,
                                             const int* __restrict__ row_idx,
                                             const int* __restrict__ row_cnt,
                                             const float* __restrict__ x,
                                             float* __restrict__ outf,
                                             float* __restrict__ bn_sum,
                                             float* __restrict__ bn_sumsq) {
  const int b = blockIdx.x >> 8;
  const int nt = blockIdx.x & 255;
  const int c = threadIdx.x;
  float s = 0.f, q = 0.f;
  for (int ii = 0; ii < 16; ++ii) {
    int n = nt * 16 + ii;
    int row = (b << 12) + n;
    int cnt = row_cnt[row];
    float acc = 0.f;
    for (int j = 0; j < cnt; ++j) {
      int e = row_idx[row * KNN + j];
      acc += yd[(((size_t)(b << 12) + e) << 8) + c];
    }
    float v = acc / (float)cnt + x[((size_t)(b * CD + c)) * NB + n];
    outf[((size_t)row << 8) + c] = v;
    s += v;
    q = fmaf(v, v, q);
  }
  atomicAdd(&bn_sum[c], s);
  atomicAdd(&bn_sumsq[c], q);
}

// ---------------- K8: BN scale/shift per channel
__global__ __launch_bounds__(256) void k_bn(const float* __restrict__ bn_sum,
                                            const float* __restrict__ bn_sumsq,
                                            const float* __restrict__ gamma,
                                            const float* __restrict__ beta,
                                            float* __restrict__ scale,
                                            float* __restrict__ shift) {
  const int c = threadIdx.x;
  const float inv = 1.f / 16384.f;
  float mean = bn_sum[c] * inv;
  float var = bn_sumsq[c] * inv - mean * mean;
  float sc = gamma[c] * rsqrtf(var + 1e-5f);
  scale[c] = sc;
  shift[c] = beta[c] - mean * sc;
}

// ---------------- K9: normalize + SiLU + transpose to [B,C,N]
__global__ __launch_bounds__(256) void k_write(const float* __restrict__ outf,
                                               const float* __restrict__ scale,
                                               const float* __restrict__ shift,
                                               float* __restrict__ out) {
  __shared__ float tile[64 * 257];
  __shared__ float sc[256], sh[256];
  const int b = blockIdx.x >> 6;
  const int n0 = (blockIdx.x & 63) << 6;
  const int tid = threadIdx.x;
  sc[tid] = scale[tid];
  sh[tid] = shift[tid];
  __syncthreads();
#pragma unroll 4
  for (int i = 0; i < 64; ++i) {
    int idx = tid + 256 * i;
    int n = idx >> 8, c = idx & 255;
    float v = outf[(((size_t)(b << 12) + n0 + n) << 8) + c];
    v = fmaf(v, sc[c], sh[c]);
    float w = v / (1.f + expf(-v));  // SiLU
    tile[n * 257 + c] = w;
  }
  __syncthreads();
  const int nl = tid & 63;
  const int cg = tid >> 6;
#pragma unroll 4
  for (int j = 0; j < 64; ++j) {
    int c = cg * 64 + j;
    out[((size_t)(b * CD + c)) * NB + n0 + nl] = tile[nl * 257 + c];
  }
}

extern "C" void kernel_launch(void* const* d_in, const int* in_sizes, int n_in,
                              void* d_out, int out_size, void* d_ws, size_t ws_size,
                              hipStream_t stream) {
  const float* x      = (const float*)d_in[0];
  const float* fc_w   = (const float*)d_in[1];
  const float* fc_b   = (const float*)d_in[2];
  const float* dist_w = (const float*)d_in[3];
  const float* gamma  = (const float*)d_in[4];
  const float* beta   = (const float*)d_in[5];
  float* out = (float*)d_out;
  char* ws = (char*)d_ws;

  const size_t OFF_EMB   = 0;
  const size_t OFF_XLIN  = (size_t)4 << 20;
  const size_t OFF_YD    = (size_t)20 << 20;
  const size_t OFF_OUTF  = (size_t)36 << 20;
  const size_t OFF_SQ    = (size_t)52 << 20;
  const size_t OFF_RIDX  = OFF_SQ + 65536;
  const size_t OFF_RCNT  = OFF_RIDX + 1572864;
  const size_t OFF_CCNT  = OFF_RCNT + 65536;
  const size_t OFF_CSTART = OFF_CCNT + 65536;
  const size_t OFF_CCUR  = OFF_CSTART + 65536;
  const size_t OFF_CLIST = OFF_CCUR + 65536;
  const size_t OFF_BNS   = OFF_CLIST + 1572864;
  const size_t OFF_BNQ   = OFF_BNS + 1024;
  const size_t OFF_SCALE = OFF_BNQ + 1024;
  const size_t OFF_SHIFT = OFF_SCALE + 1024;
  const size_t TOTAL = OFF_SHIFT + 1024;
  if (ws_size < TOTAL) return;  // insufficient workspace

  float* emb   = (float*)(ws + OFF_EMB);
  float* xlin  = (float*)(ws + OFF_XLIN);
  float* yd    = (float*)(ws + OFF_YD);
  float* outf  = (float*)(ws + OFF_OUTF);
  float* sq    = (float*)(ws + OFF_SQ);
  int* row_idx = (int*)(ws + OFF_RIDX);
  int* row_cnt = (int*)(ws + OFF_RCNT);
  int* col_cnt = (int*)(ws + OFF_CCNT);
  int* col_start = (int*)(ws + OFF_CSTART);
  int* col_cursor = (int*)(ws + OFF_CCUR);
  int* col_list = (int*)(ws + OFF_CLIST);
  float* bn_sum = (float*)(ws + OFF_BNS);
  float* bn_sumsq = (float*)(ws + OFF_BNQ);
  float* scale = (float*)(ws + OFF_SCALE);
  float* shift = (float*)(ws + OFF_SHIFT);

  hipMemsetAsync(col_cnt, 0, 65536, stream);
  hipMemsetAsync(bn_sum, 0, 2048, stream);  // bn_sum + bn_sumsq (adjacent)

  k_emb<<<256, 256, 0, stream>>>(x, dist_w, emb, sq);
  k_xlin<<<256, 256, 0, stream>>>(x, fc_w, fc_b, xlin);
  k_dist<<<256, 256, 0, stream>>>(emb, sq, row_idx, row_cnt, col_cnt);
  k_scan<<<1, 256, 0, stream>>>(col_cnt, col_start, col_cursor);
  k_fill<<<64, 256, 0, stream>>>(row_idx, row_cnt, col_cursor, col_list);
  k_yd<<<16384, 256, 0, stream>>>(xlin, col_cnt, col_start, col_list, yd);
  k_out<<<1024, 256, 0, stream>>>(yd, row_idx, row_cnt, x, outf, bn_sum, bn_sumsq);
  k_bn<<<1, 256, 0, stream>>>(bn_sum, bn_sumsq, gamma, beta, scale, shift);
  k_write<<<256, 256, 0, stream>>>(outf, scale, shift, out);
}

// Round 2
// 1329.207 us; speedup vs baseline: 1.6875x; 1.6875x over previous
//
#include <hip/hip_runtime.h>

#define NB 4096      // N = H*W
#define BATCH 4
#define CD 256       // channels
#define ED 64        // embedding dim
#define KNN 24
#define D2THR 0x42C80000u  // __float_as_uint(100.0f): d2 <= 100 <=> dist <= 10

// ---------------- K1: emb[b,n,e] = sum_c x[b,c,n]*dist_w[e,c];  sq[b,n] = sum_e emb^2
__global__ __launch_bounds__(256) void k_emb(const float* __restrict__ x,
                                             const float* __restrict__ dist_w,
                                             float* __restrict__ emb,
                                             float* __restrict__ sq) {
  __shared__ float wds[ED * CD];   // 64 KB
  __shared__ float red[64 * 4];
  const int b = blockIdx.x >> 6;
  const int n0 = (blockIdx.x & 63) << 6;
  const int tid = threadIdx.x;
  const float4* wsrc = (const float4*)dist_w;
  float4* wdst = (float4*)wds;
#pragma unroll
  for (int k = 0; k < 16; ++k) wdst[tid + 256 * k] = wsrc[tid + 256 * k];
  __syncthreads();
  const int eg = tid >> 6;   // 0..3
  const int nl = tid & 63;
  const int n = n0 + nl;
  float acc[16];
#pragma unroll
  for (int t = 0; t < 16; ++t) acc[t] = 0.f;
  const float* xb = x + (size_t)b * CD * NB + n;
#pragma unroll 4
  for (int c = 0; c < CD; ++c) {
    float xv = xb[(size_t)c * NB];
#pragma unroll
    for (int t = 0; t < 16; ++t)
      acc[t] = fmaf(xv, wds[(eg * 16 + t) * CD + c], acc[t]);
  }
  float s = 0.f;
#pragma unroll
  for (int t = 0; t < 16; ++t) s = fmaf(acc[t], acc[t], s);
  float* ebase = emb + ((size_t)(b * NB + n)) * ED + eg * 16;
#pragma unroll
  for (int t4 = 0; t4 < 4; ++t4)
    ((float4*)ebase)[t4] = make_float4(acc[4 * t4], acc[4 * t4 + 1], acc[4 * t4 + 2], acc[4 * t4 + 3]);
  red[nl * 4 + eg] = s;
  __syncthreads();
  if (tid < 64)
    sq[b * NB + n0 + tid] = red[tid * 4] + red[tid * 4 + 1] + red[tid * 4 + 2] + red[tid * 4 + 3];
}

// ---------------- K2: X_lin[b,n,c] = sum_k x[b,k,n]*fc_w[c,k] + fc_b[c]
__global__ __launch_bounds__(256) void k_xlin(const float* __restrict__ x,
                                              const float* __restrict__ fc_w,
                                              const float* __restrict__ fc_b,
                                              float* __restrict__ xlin) {
  __shared__ float xt[64 * 64];     // [k][n]
  __shared__ float wt[64 * 260];    // [k][c] padded
  const int b = blockIdx.x >> 6;
  const int n0 = (blockIdx.x & 63) << 6;
  const int tid = threadIdx.x;
  const int nl4 = tid & 15;   // n = 4*nl4 + i
  const int cg = tid >> 4;    // c = 4*cg + 64*j + l
  float acc[4][16];
#pragma unroll
  for (int i = 0; i < 4; ++i)
#pragma unroll
    for (int j = 0; j < 16; ++j) acc[i][j] = 0.f;

  for (int kt = 0; kt < 4; ++kt) {
    __syncthreads();
#pragma unroll 4
    for (int i = 0; i < 16; ++i) {
      int idx = tid + 256 * i;
      int k = idx >> 6, n = idx & 63;
      xt[idx] = x[((size_t)(b * CD + kt * 64 + k)) * NB + n0 + n];
    }
#pragma unroll 4
    for (int i = 0; i < 16; ++i) {
      int q = tid + 256 * i;
      int c = q >> 4, k4 = (q & 15) * 4;
      float4 v = *(const float4*)&fc_w[(size_t)c * CD + kt * 64 + k4];
      wt[(k4 + 0) * 260 + c] = v.x;
      wt[(k4 + 1) * 260 + c] = v.y;
      wt[(k4 + 2) * 260 + c] = v.z;
      wt[(k4 + 3) * 260 + c] = v.w;
    }
    __syncthreads();
#pragma unroll 2
    for (int k = 0; k < 64; ++k) {
      float4 xv = *(const float4*)&xt[k * 64 + 4 * nl4];
#pragma unroll
      for (int j = 0; j < 4; ++j) {
        float4 wv = *(const float4*)&wt[k * 260 + 4 * cg + 64 * j];
        const float* wp = &wv.x;
#pragma unroll
        for (int l = 0; l < 4; ++l) {
          acc[0][4 * j + l] = fmaf(xv.x, wp[l], acc[0][4 * j + l]);
          acc[1][4 * j + l] = fmaf(xv.y, wp[l], acc[1][4 * j + l]);
          acc[2][4 * j + l] = fmaf(xv.z, wp[l], acc[2][4 * j + l]);
          acc[3][4 * j + l] = fmaf(xv.w, wp[l], acc[3][4 * j + l]);
        }
      }
    }
  }
#pragma unroll
  for (int i = 0; i < 4; ++i) {
    int n = n0 + 4 * nl4 + i;
    float* dst = xlin + ((size_t)(b * NB + n)) * CD;
#pragma unroll
    for (int j = 0; j < 4; ++j) {
      int c = 4 * cg + 64 * j;
      float4 bv = *(const float4*)&fc_b[c];
      float4 o;
      o.x = acc[i][4 * j + 0] + bv.x;
      o.y = acc[i][4 * j + 1] + bv.y;
      o.z = acc[i][4 * j + 2] + bv.z;
      o.w = acc[i][4 * j + 3] + bv.w;
      *(float4*)&dst[c] = o;
    }
  }
}

// ---------------- K3 v2: d2 + exact top-24 (rank by d2, ties by index) + threshold
// 512 threads, 64 rows/block, 128-m chunks, drain parallelized 4x with private lists.
__global__ __launch_bounds__(512) void k_dist(const float* __restrict__ emb,
                                              const float* __restrict__ sq,
                                              int* __restrict__ row_idx,
                                              int* __restrict__ row_cnt,
                                              int* __restrict__ col_cnt) {
  __shared__ float eN[64 * 68];                 // 17.4 KB
  __shared__ float eM[128 * 68];                // 34.8 KB
  __shared__ unsigned int d2t[64 * 129];        // 33.0 KB
  __shared__ unsigned long long lists[256 * 25];// 51.2 KB (24 + 1 pad; stride 25 breaks conflicts)
  __shared__ float sqN[64];
  __shared__ float sqM[128];

  const int b = blockIdx.x >> 6;
  const int n0 = (blockIdx.x & 63) << 6;
  const int tid = threadIdx.x;
  const float* embB = emb + (size_t)b * NB * ED;

  // stage eN: 64 rows x 16 float4
#pragma unroll
  for (int k = 0; k < 2; ++k) {
    int q = tid + 512 * k;
    int r = q >> 4, e4 = q & 15;
    *(float4*)&eN[r * 68 + e4 * 4] = *(const float4*)&embB[(size_t)(n0 + r) * ED + e4 * 4];
  }
  if (tid < 64) sqN[tid] = sq[b * NB + n0 + tid];
#pragma unroll
  for (int k = 0; k < 13; ++k) {
    int q = tid + 512 * k;
    if (q < 6400) lists[q] = ~0ULL;
  }
  __syncthreads();

  const int rg = tid >> 5;   // 0..15  rows rg+16i
  const int mg = tid & 31;   // 0..31  cols mg+32j
  const int dr = tid & 63;   // drain row
  const int ds = tid >> 6;   // drain seg (valid for tid<256)
  const int lb = ((ds << 6) | dr) * 25;
  unsigned long long worst = ~0ULL;

  for (int ci = 0; ci < 32; ++ci) {
    const int m0 = ci << 7;
    // stage eM: 128 x 16 float4 (concurrent with previous drain; disjoint LDS)
#pragma unroll
    for (int k = 0; k < 4; ++k) {
      int q = tid + 512 * k;
      int m = q >> 4, e4 = q & 15;
      *(float4*)&eM[m * 68 + e4 * 4] = *(const float4*)&embB[(size_t)(m0 + m) * ED + e4 * 4];
    }
    if (tid < 128) sqM[tid] = sq[b * NB + m0 + tid];
    __syncthreads();  // B1: eM ready AND previous drain done (d2t free)

    float acc[4][4];
#pragma unroll
    for (int i = 0; i < 4; ++i)
#pragma unroll
      for (int j = 0; j < 4; ++j) acc[i][j] = 0.f;

#pragma unroll
    for (int e4 = 0; e4 < 16; ++e4) {
      float4 av[4], bv[4];
#pragma unroll
      for (int i = 0; i < 4; ++i) av[i] = *(const float4*)&eN[(rg + 16 * i) * 68 + e4 * 4];
#pragma unroll
      for (int j = 0; j < 4; ++j) bv[j] = *(const float4*)&eM[(mg + 32 * j) * 68 + e4 * 4];
#pragma unroll
      for (int i = 0; i < 4; ++i)
#pragma unroll
        for (int j = 0; j < 4; ++j) {
          acc[i][j] = fmaf(av[i].x, bv[j].x, acc[i][j]);
          acc[i][j] = fmaf(av[i].y, bv[j].y, acc[i][j]);
          acc[i][j] = fmaf(av[i].z, bv[j].z, acc[i][j]);
          acc[i][j] = fmaf(av[i].w, bv[j].w, acc[i][j]);
        }
    }
#pragma unroll
    for (int i = 0; i < 4; ++i) {
      int r = rg + 16 * i;
      float sn = sqN[r];
#pragma unroll
      for (int j = 0; j < 4; ++j) {
        int ml = mg + 32 * j;
        float d2 = fmaxf(sn + sqM[ml] - 2.f * acc[i][j], 0.f);
        d2t[r * 129 + ml] = __float_as_uint(d2);
      }
    }
    __syncthreads();  // B2: d2t ready

    if (tid < 256) {
      const int mb = ds * 32;
#pragma unroll 4
      for (int jj = 0; jj < 32; ++jj) {
        unsigned long long p =
            ((unsigned long long)d2t[dr * 129 + mb + jj] << 32) | (unsigned int)(m0 + mb + jj);
        if (p < worst) {
          int pos = 23;
          while (pos > 0 && lists[lb + pos - 1] > p) {
            lists[lb + pos] = lists[lb + pos - 1];
            --pos;
          }
          lists[lb + pos] = p;
          worst = lists[lb + 23];
        }
      }
    }
    // threads >=256 proceed to stage next eM; B1 next iter orders drain vs d2t overwrite
  }
  __syncthreads();

  if (tid < 64) {
    const int r = tid;
    int pp[4] = {0, 0, 0, 0};
    unsigned long long h[4];
#pragma unroll
    for (int s = 0; s < 4; ++s) h[s] = lists[((s << 6) | r) * 25];
    int cnt = 0;
    const int base = (b * NB + n0 + r) * KNN;
    for (int k = 0; k < 24; ++k) {
      int bs = 0;
      unsigned long long mv = h[0];
#pragma unroll
      for (int s = 1; s < 4; ++s)
        if (h[s] < mv) { mv = h[s]; bs = s; }
      if ((unsigned int)(mv >> 32) > D2THR) break;  // sorted: nothing further passes
      int mi = (int)(mv & 0xffffffffu);
      row_idx[base + cnt] = mi;
      atomicAdd(&col_cnt[b * NB + mi], 1);
      ++cnt;
      int np = ++pp[bs];
      h[bs] = lists[((bs << 6) | r) * 25 + np];  // np==24 only on final iter (pad slot, unused)
    }
    row_cnt[b * NB + n0 + r] = cnt;
  }
}

// ---------------- K4: exclusive scan of col_cnt (16384 entries), 1 block
__global__ __launch_bounds__(256) void k_scan(const int* __restrict__ col_cnt,
                                              int* __restrict__ col_start,
                                              int* __restrict__ col_cursor) {
  __shared__ int part[256];
  const int tid = threadIdx.x;
  const int base = tid * 64;
  int s = 0;
  for (int j = 0; j < 64; ++j) s += col_cnt[base + j];
  part[tid] = s;
  __syncthreads();
  for (int off = 1; off < 256; off <<= 1) {
    int v = (tid >= off) ? part[tid - off] : 0;
    __syncthreads();
    part[tid] += v;
    __syncthreads();
  }
  int run = part[tid] - s;
  for (int j = 0; j < 64; ++j) {
    col_start[base + j] = run;
    col_cursor[base + j] = run;
    run += col_cnt[base + j];
  }
}

// ---------------- K5: fill CSC column lists
__global__ __launch_bounds__(256) void k_fill(const int* __restrict__ row_idx,
                                              const int* __restrict__ row_cnt,
                                              int* __restrict__ col_cursor,
                                              int* __restrict__ col_list) {
  const int row = blockIdx.x * 256 + threadIdx.x;  // b*NB+n
  const int b = row >> 12;
  const int n = row & 4095;
  const int cnt = row_cnt[row];
  for (int j = 0; j < cnt; ++j) {
    int m = row_idx[row * KNN + j];
    int pos = atomicAdd(&col_cursor[(b << 12) + m], 1);
    col_list[pos] = n;
  }
}

// ---------------- K6: Yd[e,c] = (sum_{m in col(e)} X_lin[m,c]) / De[e]  (float4, 4 e's/block)
__global__ __launch_bounds__(256) void k_yd(const float* __restrict__ xlin,
                                            const int* __restrict__ col_cnt,
                                            const int* __restrict__ col_start,
                                            const int* __restrict__ col_list,
                                            float* __restrict__ yd) {
  const int le = threadIdx.x >> 6;        // wave-uniform e select
  const int c4 = threadIdx.x & 63;
  const int be = blockIdx.x * 4 + le;     // b*NB + e
  const int b = be >> 12;
  const int deg = col_cnt[be];
  const int start = col_start[be];
  float4 acc = make_float4(0.f, 0.f, 0.f, 0.f);
  for (int j = 0; j < deg; ++j) {
    int m = col_list[start + j];
    float4 v = *(const float4*)&xlin[(((size_t)(b << 12) + m) << 8) + c4 * 4];
    acc.x += v.x; acc.y += v.y; acc.z += v.z; acc.w += v.w;
  }
  float inv = 1.f / (float)deg;
  acc.x *= inv; acc.y *= inv; acc.z *= inv; acc.w *= inv;
  *(float4*)&yd[((size_t)be << 8) + c4 * 4] = acc;
}

// ---------------- K7: g[n,c] = (sum_{e in row(n)} Yd[e,c]) / Dv[n]   (no residual here)
__global__ __launch_bounds__(256) void k_out2(const float* __restrict__ yd,
                                              const int* __restrict__ row_idx,
                                              const int* __restrict__ row_cnt,
                                              float* __restrict__ outf) {
  const int b = blockIdx.x >> 8;
  const int nt = blockIdx.x & 255;
  const int le = threadIdx.x >> 6;   // wave-uniform n select
  const int c4 = threadIdx.x & 63;
  for (int ii = 0; ii < 4; ++ii) {
    int n = nt * 16 + le * 4 + ii;
    int row = (b << 12) + n;
    int cnt = row_cnt[row];
    float4 acc = make_float4(0.f, 0.f, 0.f, 0.f);
    for (int j = 0; j < cnt; ++j) {
      int e = row_idx[row * KNN + j];
      float4 v = *(const float4*)&yd[(((size_t)(b << 12) + e) << 8) + c4 * 4];
      acc.x += v.x; acc.y += v.y; acc.z += v.z; acc.w += v.w;
    }
    float inv = 1.f / (float)cnt;
    acc.x *= inv; acc.y *= inv; acc.z *= inv; acc.w *= inv;
    *(float4*)&outf[((size_t)row << 8) + c4 * 4] = acc;
  }
}

// ---------------- K8: outf += x (residual, via LDS transpose); accumulate BN sums
__global__ __launch_bounds__(256) void k_res_bn(const float* __restrict__ x,
                                                float* __restrict__ outf,
                                                float* __restrict__ bn_sum,
                                                float* __restrict__ bn_sumsq) {
  __shared__ float xt[256 * 69];   // [c][n] padded: (69=5 mod 32 -> conflict-free col reads)
  const int b = blockIdx.x >> 6;
  const int n0 = (blockIdx.x & 63) << 6;
  const int tid = threadIdx.x;
  // stage x tile: 256 c x 64 n; lanes cooperate along n for coalescing
#pragma unroll 4
  for (int k = 0; k < 16; ++k) {
    int q = tid + 256 * k;          // 4096 float4
    int c = q >> 4, f = q & 15;
    float4 v = *(const float4*)&x[((size_t)(b * CD + c)) * NB + n0 + 4 * f];
    xt[c * 69 + 4 * f + 0] = v.x;
    xt[c * 69 + 4 * f + 1] = v.y;
    xt[c * 69 + 4 * f + 2] = v.z;
    xt[c * 69 + 4 * f + 3] = v.w;
  }
  __syncthreads();
  float s = 0.f, q = 0.f;
  const size_t rbase = ((size_t)((b << 12) + n0)) << 8;
#pragma unroll 4
  for (int i = 0; i < 64; ++i) {
    float v = outf[rbase + (size_t)i * 256 + tid] + xt[tid * 69 + i];
    outf[rbase + (size_t)i * 256 + tid] = v;
    s += v;
    q = fmaf(v, v, q);
  }
  atomicAdd(&bn_sum[tid], s);
  atomicAdd(&bn_sumsq[tid], q);
}

// ---------------- K9: BN scale/shift per channel
__global__ __launch_bounds__(256) void k_bn(const float* __restrict__ bn_sum,
                                            const float* __restrict__ bn_sumsq,
                                            const float* __restrict__ gamma,
                                            const float* __restrict__ beta,
                                            float* __restrict__ scale,
                                            float* __restrict__ shift) {
  const int c = threadIdx.x;
  const float inv = 1.f / 16384.f;
  float mean = bn_sum[c] * inv;
  float var = bn_sumsq[c] * inv - mean * mean;
  float sc = gamma[c] * rsqrtf(var + 1e-5f);
  scale[c] = sc;
  shift[c] = beta[c] - mean * sc;
}

// ---------------- K10: normalize + SiLU + transpose to [B,C,N]
__global__ __launch_bounds__(256) void k_write(const float* __restrict__ outf,
                                               const float* __restrict__ scale,
                                               const float* __restrict__ shift,
                                               float* __restrict__ out) {
  __shared__ float tile[64 * 257];
  __shared__ float sc[256], sh[256];
  const int b = blockIdx.x >> 6;
  const int n0 = (blockIdx.x & 63) << 6;
  const int tid = threadIdx.x;
  sc[tid] = scale[tid];
  sh[tid] = shift[tid];
  __syncthreads();
#pragma unroll 4
  for (int i = 0; i < 64; ++i) {
    int idx = tid + 256 * i;
    int n = idx >> 8, c = idx & 255;
    float v = outf[(((size_t)(b << 12) + n0 + n) << 8) + c];
    v = fmaf(v, sc[c], sh[c]);
    float w = v / (1.f + expf(-v));  // SiLU
    tile[n * 257 + c] = w;
  }
  __syncthreads();
  const int nl = tid & 63;
  const int cg = tid >> 6;
#pragma unroll 4
  for (int j = 0; j < 64; ++j) {
    int c = cg * 64 + j;
    out[((size_t)(b * CD + c)) * NB + n0 + nl] = tile[nl * 257 + c];
  }
}

extern "C" void kernel_launch(void* const* d_in, const int* in_sizes, int n_in,
                              void* d_out, int out_size, void* d_ws, size_t ws_size,
                              hipStream_t stream) {
  const float* x      = (const float*)d_in[0];
  const float* fc_w   = (const float*)d_in[1];
  const float* fc_b   = (const float*)d_in[2];
  const float* dist_w = (const float*)d_in[3];
  const float* gamma  = (const float*)d_in[4];
  const float* beta   = (const float*)d_in[5];
  float* out = (float*)d_out;
  char* ws = (char*)d_ws;

  const size_t OFF_EMB   = 0;
  const size_t OFF_XLIN  = (size_t)4 << 20;
  const size_t OFF_YD    = (size_t)20 << 20;
  const size_t OFF_OUTF  = (size_t)36 << 20;
  const size_t OFF_SQ    = (size_t)52 << 20;
  const size_t OFF_RIDX  = OFF_SQ + 65536;
  const size_t OFF_RCNT  = OFF_RIDX + 1572864;
  const size_t OFF_CCNT  = OFF_RCNT + 65536;
  const size_t OFF_CSTART = OFF_CCNT + 65536;
  const size_t OFF_CCUR  = OFF_CSTART + 65536;
  const size_t OFF_CLIST = OFF_CCUR + 65536;
  const size_t OFF_BNS   = OFF_CLIST + 1572864;
  const size_t OFF_BNQ   = OFF_BNS + 1024;
  const size_t OFF_SCALE = OFF_BNQ + 1024;
  const size_t OFF_SHIFT = OFF_SCALE + 1024;
  const size_t TOTAL = OFF_SHIFT + 1024;
  if (ws_size < TOTAL) return;

  float* emb   = (float*)(ws + OFF_EMB);
  float* xlin  = (float*)(ws + OFF_XLIN);
  float* yd    = (float*)(ws + OFF_YD);
  float* outf  = (float*)(ws + OFF_OUTF);
  float* sq    = (float*)(ws + OFF_SQ);
  int* row_idx = (int*)(ws + OFF_RIDX);
  int* row_cnt = (int*)(ws + OFF_RCNT);
  int* col_cnt = (int*)(ws + OFF_CCNT);
  int* col_start = (int*)(ws + OFF_CSTART);
  int* col_cursor = (int*)(ws + OFF_CCUR);
  int* col_list = (int*)(ws + OFF_CLIST);
  float* bn_sum = (float*)(ws + OFF_BNS);
  float* bn_sumsq = (float*)(ws + OFF_BNQ);
  float* scale = (float*)(ws + OFF_SCALE);
  float* shift = (float*)(ws + OFF_SHIFT);

  hipMemsetAsync(col_cnt, 0, 65536, stream);
  hipMemsetAsync(bn_sum, 0, 2048, stream);  // bn_sum + bn_sumsq (adjacent)

  k_emb<<<256, 256, 0, stream>>>(x, dist_w, emb, sq);
  k_xlin<<<256, 256, 0, stream>>>(x, fc_w, fc_b, xlin);
  k_dist<<<256, 512, 0, stream>>>(emb, sq, row_idx, row_cnt, col_cnt);
  k_scan<<<1, 256, 0, stream>>>(col_cnt, col_start, col_cursor);
  k_fill<<<64, 256, 0, stream>>>(row_idx, row_cnt, col_cursor, col_list);
  k_yd<<<4096, 256, 0, stream>>>(xlin, col_cnt, col_start, col_list, yd);
  k_out2<<<1024, 256, 0, stream>>>(yd, row_idx, row_cnt, outf);
  k_res_bn<<<256, 256, 0, stream>>>(x, outf, bn_sum, bn_sumsq);
  k_bn<<<1, 256, 0, stream>>>(bn_sum, bn_sumsq, gamma, beta, scale, shift);
  k_write<<<256, 256, 0, stream>>>(outf, scale, shift, out);
}

// Round 4
// 1089.582 us; speedup vs baseline: 2.0586x; 1.2199x over previous
//
#include <hip/hip_runtime.h>

#define NB 4096      // N = H*W
#define BATCH 4
#define CD 256       // channels
#define ED 64        // embedding dim
#define KNN 24

typedef __attribute__((ext_vector_type(8))) short bf16x8;
typedef __attribute__((ext_vector_type(4))) float f32x4;

__device__ __forceinline__ unsigned short f2bf(float x) {
  unsigned u = __float_as_uint(x);
  unsigned r = (u + 0x7fffu + ((u >> 16) & 1u)) >> 16;
  return (unsigned short)r;
}

// ---------------- K1: emb = x @ dist_w^T  -> emb_hl (bf16 hi/lo, XOR-swizzled chunks) + sq (fp32)
// emb_hl row layout (256 B): 16 chunks of 16 B; logical chunks 0..7 = hi[e], 8..15 = lo[e];
// physical position = logical ^ (n & 15)  (conflict-free MFMA fragment reads from LDS)
__global__ __launch_bounds__(256) void k_emb(const float* __restrict__ x,
                                             const float* __restrict__ dist_w,
                                             unsigned* __restrict__ emb_hl,
                                             float* __restrict__ sq) {
  __shared__ float wds[ED * CD];   // 64 KB
  __shared__ float red[64 * 4];
  const int b = blockIdx.x >> 6;
  const int n0 = (blockIdx.x & 63) << 6;
  const int tid = threadIdx.x;
  const float4* wsrc = (const float4*)dist_w;
  float4* wdst = (float4*)wds;
#pragma unroll
  for (int k = 0; k < 16; ++k) wdst[tid + 256 * k] = wsrc[tid + 256 * k];
  __syncthreads();
  const int eg = tid >> 6;   // 0..3
  const int nl = tid & 63;
  const int n = n0 + nl;
  float acc[16];
#pragma unroll
  for (int t = 0; t < 16; ++t) acc[t] = 0.f;
  const float* xb = x + (size_t)b * CD * NB + n;
#pragma unroll 4
  for (int c = 0; c < CD; ++c) {
    float xv = xb[(size_t)c * NB];
#pragma unroll
    for (int t = 0; t < 16; ++t)
      acc[t] = fmaf(xv, wds[(eg * 16 + t) * CD + c], acc[t]);
  }
  float s = 0.f;
#pragma unroll
  for (int t = 0; t < 16; ++t) s = fmaf(acc[t], acc[t], s);
  // split to bf16 hi/lo
  unsigned hw[8], lw[8];
#pragma unroll
  for (int i = 0; i < 8; ++i) {
    unsigned short h0 = f2bf(acc[2 * i]);
    unsigned short h1 = f2bf(acc[2 * i + 1]);
    float l0f = acc[2 * i] - __uint_as_float((unsigned)h0 << 16);
    float l1f = acc[2 * i + 1] - __uint_as_float((unsigned)h1 << 16);
    hw[i] = (unsigned)h0 | ((unsigned)h1 << 16);
    lw[i] = (unsigned)f2bf(l0f) | ((unsigned)f2bf(l1f) << 16);
  }
  uint4* g = (uint4*)emb_hl;
  const size_t gb = ((size_t)(b * NB + n)) * 16;
  const int k15 = n & 15;
  g[gb + ((2 * eg) ^ k15)]     = make_uint4(hw[0], hw[1], hw[2], hw[3]);
  g[gb + ((2 * eg + 1) ^ k15)] = make_uint4(hw[4], hw[5], hw[6], hw[7]);
  g[gb + ((8 + 2 * eg) ^ k15)]     = make_uint4(lw[0], lw[1], lw[2], lw[3]);
  g[gb + ((8 + 2 * eg + 1) ^ k15)] = make_uint4(lw[4], lw[5], lw[6], lw[7]);
  red[nl * 4 + eg] = s;
  __syncthreads();
  if (tid < 64)
    sq[b * NB + n0 + tid] = red[tid * 4] + red[tid * 4 + 1] + red[tid * 4 + 2] + red[tid * 4 + 3];
}

// ---------------- K2: X_lin[b,n,c] = sum_k x[b,k,n]*fc_w[c,k] + fc_b[c]
__global__ __launch_bounds__(256) void k_xlin(const float* __restrict__ x,
                                              const float* __restrict__ fc_w,
                                              const float* __restrict__ fc_b,
                                              float* __restrict__ xlin) {
  __shared__ float xt[64 * 64];     // [k][n]
  __shared__ float wt[64 * 260];    // [k][c] padded
  const int b = blockIdx.x >> 6;
  const int n0 = (blockIdx.x & 63) << 6;
  const int tid = threadIdx.x;
  const int nl4 = tid & 15;
  const int cg = tid >> 4;
  float acc[4][16];
#pragma unroll
  for (int i = 0; i < 4; ++i)
#pragma unroll
    for (int j = 0; j < 16; ++j) acc[i][j] = 0.f;

  for (int kt = 0; kt < 4; ++kt) {
    __syncthreads();
#pragma unroll 4
    for (int i = 0; i < 16; ++i) {
      int idx = tid + 256 * i;
      int k = idx >> 6, n = idx & 63;
      xt[idx] = x[((size_t)(b * CD + kt * 64 + k)) * NB + n0 + n];
    }
#pragma unroll 4
    for (int i = 0; i < 16; ++i) {
      int q = tid + 256 * i;
      int c = q >> 4, k4 = (q & 15) * 4;
      float4 v = *(const float4*)&fc_w[(size_t)c * CD + kt * 64 + k4];
      wt[(k4 + 0) * 260 + c] = v.x;
      wt[(k4 + 1) * 260 + c] = v.y;
      wt[(k4 + 2) * 260 + c] = v.z;
      wt[(k4 + 3) * 260 + c] = v.w;
    }
    __syncthreads();
#pragma unroll 2
    for (int k = 0; k < 64; ++k) {
      float4 xv = *(const float4*)&xt[k * 64 + 4 * nl4];
#pragma unroll
      for (int j = 0; j < 4; ++j) {
        float4 wv = *(const float4*)&wt[k * 260 + 4 * cg + 64 * j];
        const float* wp = &wv.x;
#pragma unroll
        for (int l = 0; l < 4; ++l) {
          acc[0][4 * j + l] = fmaf(xv.x, wp[l], acc[0][4 * j + l]);
          acc[1][4 * j + l] = fmaf(xv.y, wp[l], acc[1][4 * j + l]);
          acc[2][4 * j + l] = fmaf(xv.z, wp[l], acc[2][4 * j + l]);
          acc[3][4 * j + l] = fmaf(xv.w, wp[l], acc[3][4 * j + l]);
        }
      }
    }
  }
#pragma unroll
  for (int i = 0; i < 4; ++i) {
    int n = n0 + 4 * nl4 + i;
    float* dst = xlin + ((size_t)(b * NB + n)) * CD;
#pragma unroll
    for (int j = 0; j < 4; ++j) {
      int c = 4 * cg + 64 * j;
      float4 bv = *(const float4*)&fc_b[c];
      float4 o;
      o.x = acc[i][4 * j + 0] + bv.x;
      o.y = acc[i][4 * j + 1] + bv.y;
      o.z = acc[i][4 * j + 2] + bv.z;
      o.w = acc[i][4 * j + 3] + bv.w;
      *(float4*)&dst[c] = o;
    }
  }
}

// ---------------- K3 v4: bf16-split MFMA Gram + exact top-24 with FULL u64 keys (d2bits<<32 | m)
// 512 thr, 64 rows/block, 64-m chunks. LDS ~117 KB (grid=256 -> 1 block/CU anyway).
__global__ __launch_bounds__(512) void k_dist(const unsigned* __restrict__ emb_hl,
                                              const float* __restrict__ sq,
                                              int* __restrict__ row_idx,
                                              int* __restrict__ row_cnt,
                                              int* __restrict__ col_cnt) {
  __shared__ unsigned eN[64 * 64];              // 16 KB (row = 64 uints, swizzled chunks)
  __shared__ unsigned eM[64 * 64];              // 16 KB
  __shared__ unsigned long long d2t[64 * 65];   // 33.3 KB full keys, stride 65
  __shared__ unsigned long long lists[256 * 25];// 51.2 KB
  __shared__ float sqN[64];
  __shared__ float sqM[64];

  const int b = blockIdx.x >> 6;
  const int n0 = (blockIdx.x & 63) << 6;
  const int tid = threadIdx.x;
  const uint4* embg = (const uint4*)emb_hl;
  const size_t bbase = (size_t)b * NB;

  // stage eN (64 rows x 16 uint4)
#pragma unroll
  for (int k = 0; k < 2; ++k) {
    int q = tid + 512 * k;
    int r = q >> 4, ch = q & 15;
    *(uint4*)&eN[r * 64 + ch * 4] = embg[(bbase + n0 + r) * 16 + ch];
  }
  if (tid < 64) sqN[tid] = sq[b * NB + n0 + tid];
#pragma unroll
  for (int k = 0; k < 13; ++k) {
    int q = tid + 512 * k;
    if (q < 6400) lists[q] = ~0ULL;
  }
  __syncthreads();

  const int w = tid >> 6, lane = tid & 63;
  const int quad = lane >> 4, lr = lane & 15;
  const int rt = w >> 1;              // row tile 0..3
  const int ct0 = (w & 1) * 2;        // first of 2 col tiles
  const int rowA = rt * 16 + lr;
  const int rowB0 = ct0 * 16 + lr;
  const int rowB1 = rowB0 + 16;

  const int s = tid >> 6;             // drain segment (tid<256)
  const int dr = tid & 63;            // drain row
  const int lb = ((s << 6) | dr) * 25;
  unsigned long long worst = ~0ULL;

  for (int ci = 0; ci < 64; ++ci) {
    const int m0 = ci << 6;
    // stage eM chunk
#pragma unroll
    for (int k = 0; k < 2; ++k) {
      int q = tid + 512 * k;
      int r = q >> 4, ch = q & 15;
      *(uint4*)&eM[r * 64 + ch * 4] = embg[(bbase + m0 + r) * 16 + ch];
    }
    if (tid < 64) sqM[tid] = sq[b * NB + m0 + tid];
    __syncthreads();  // B1: eM ready AND previous drain done

    f32x4 acc0 = {0.f, 0.f, 0.f, 0.f};
    f32x4 acc1 = {0.f, 0.f, 0.f, 0.f};
#pragma unroll
    for (int kk = 0; kk < 2; ++kk) {
      const int cb = quad + 4 * kk;   // logical hi chunk
      bf16x8 a_hi = *(const bf16x8*)&eN[rowA * 64 + ((cb) ^ lr) * 4];
      bf16x8 a_lo = *(const bf16x8*)&eN[rowA * 64 + ((cb + 8) ^ lr) * 4];
      bf16x8 b0_hi = *(const bf16x8*)&eM[rowB0 * 64 + ((cb) ^ lr) * 4];
      bf16x8 b0_lo = *(const bf16x8*)&eM[rowB0 * 64 + ((cb + 8) ^ lr) * 4];
      bf16x8 b1_hi = *(const bf16x8*)&eM[rowB1 * 64 + ((cb) ^ lr) * 4];
      bf16x8 b1_lo = *(const bf16x8*)&eM[rowB1 * 64 + ((cb + 8) ^ lr) * 4];
      acc0 = __builtin_amdgcn_mfma_f32_16x16x32_bf16(a_hi, b0_hi, acc0, 0, 0, 0);
      acc0 = __builtin_amdgcn_mfma_f32_16x16x32_bf16(a_hi, b0_lo, acc0, 0, 0, 0);
      acc0 = __builtin_amdgcn_mfma_f32_16x16x32_bf16(a_lo, b0_hi, acc0, 0, 0, 0);
      acc1 = __builtin_amdgcn_mfma_f32_16x16x32_bf16(a_hi, b1_hi, acc1, 0, 0, 0);
      acc1 = __builtin_amdgcn_mfma_f32_16x16x32_bf16(a_hi, b1_lo, acc1, 0, 0, 0);
      acc1 = __builtin_amdgcn_mfma_f32_16x16x32_bf16(a_lo, b1_hi, acc1, 0, 0, 0);
    }
    // pack full-precision keys into d2t (C layout: col=lane&15, row=quad*4+reg)
#pragma unroll
    for (int reg = 0; reg < 4; ++reg) {
      int row = rt * 16 + quad * 4 + reg;
      float sn = sqN[row];
      int c0 = ct0 * 16 + lr;
      int c1 = c0 + 16;
      float d20 = fmaxf(sn + sqM[c0] - 2.f * acc0[reg], 0.f);
      float d21 = fmaxf(sn + sqM[c1] - 2.f * acc1[reg], 0.f);
      d2t[row * 65 + c0] = ((unsigned long long)__float_as_uint(d20) << 32) | (unsigned)(m0 + c0);
      d2t[row * 65 + c1] = ((unsigned long long)__float_as_uint(d21) << 32) | (unsigned)(m0 + c1);
    }
    __syncthreads();  // B2: d2t ready

    if (tid < 256) {
      const int mb = s * 16;
#pragma unroll 4
      for (int jj = 0; jj < 16; ++jj) {
        unsigned long long p = d2t[dr * 65 + mb + jj];
        if (p < worst) {
          int pos = 23;
          while (pos > 0 && lists[lb + pos - 1] > p) {
            lists[lb + pos] = lists[lb + pos - 1];
            --pos;
          }
          lists[lb + pos] = p;
          worst = lists[lb + 23];
        }
      }
    }
    // waves >=256 proceed to stage next eM; B1 next iter orders drain vs d2t overwrite
  }
  __syncthreads();

  if (tid < 64) {
    const int r = tid;
    const int n = n0 + r;
    int pp[4] = {0, 0, 0, 0};
    unsigned long long h[4];
#pragma unroll
    for (int t = 0; t < 4; ++t) h[t] = lists[((t << 6) | r) * 25];
    int cnt = 0;
    const int base = (b * NB + n) * KNN;
    for (int k = 0; k < 24; ++k) {
      int bs = 0;
      unsigned long long mv = h[0];
#pragma unroll
      for (int t = 1; t < 4; ++t)
        if (h[t] < mv) { mv = h[t]; bs = t; }
      if ((unsigned)(mv >> 32) > 0x42C80000u) break;  // d2 > 100 -> done (sorted)
      int mi = (int)(mv & 0xFFFFFFFFu);
      row_idx[base + cnt] = mi;
      atomicAdd(&col_cnt[b * NB + mi], 1);
      ++cnt;
      int np = ++pp[bs];
      h[bs] = lists[((bs << 6) | r) * 25 + np];  // slot 24 = sentinel pad
    }
    row_cnt[b * NB + n] = cnt;
#pragma unroll 4
    for (int j = cnt; j < 24; ++j) row_idx[base + j] = n;  // pad with self (valid gather idx)
  }
}

// ---------------- K4: exclusive scan of col_cnt (16384 entries), 1 block
__global__ __launch_bounds__(256) void k_scan(const int* __restrict__ col_cnt,
                                              int* __restrict__ col_start,
                                              int* __restrict__ col_cursor) {
  __shared__ int part[256];
  const int tid = threadIdx.x;
  const int base = tid * 64;
  int s = 0;
  for (int j = 0; j < 64; ++j) s += col_cnt[base + j];
  part[tid] = s;
  __syncthreads();
  for (int off = 1; off < 256; off <<= 1) {
    int v = (tid >= off) ? part[tid - off] : 0;
    __syncthreads();
    part[tid] += v;
    __syncthreads();
  }
  int run = part[tid] - s;
  for (int j = 0; j < 64; ++j) {
    col_start[base + j] = run;
    col_cursor[base + j] = run;
    run += col_cnt[base + j];
  }
}

// ---------------- K5: fill CSC column lists
__global__ __launch_bounds__(256) void k_fill(const int* __restrict__ row_idx,
                                              const int* __restrict__ row_cnt,
                                              int* __restrict__ col_cursor,
                                              int* __restrict__ col_list) {
  const int row = blockIdx.x * 256 + threadIdx.x;
  const int b = row >> 12;
  const int cnt = row_cnt[row];
  for (int j = 0; j < cnt; ++j) {
    int m = row_idx[row * KNN + j];
    int pos = atomicAdd(&col_cursor[(b << 12) + m], 1);
    col_list[pos] = row & 4095;
  }
}

// ---------------- K6: Yd[e,c] = (sum_{m in col(e)} X_lin[m,c]) / De[e]
__global__ __launch_bounds__(256) void k_yd(const float* __restrict__ xlin,
                                            const int* __restrict__ col_cnt,
                                            const int* __restrict__ col_start,
                                            const int* __restrict__ col_list,
                                            float* __restrict__ yd) {
  const int le = threadIdx.x >> 6;
  const int c4 = threadIdx.x & 63;
  const int be = blockIdx.x * 4 + le;
  const int b = be >> 12;
  const int deg = col_cnt[be];
  const int start = col_start[be];
  float4 acc = make_float4(0.f, 0.f, 0.f, 0.f);
  int j = 0;
  for (; j + 3 < deg; j += 4) {
    int ma = col_list[start + j], mb2 = col_list[start + j + 1];
    int mc = col_list[start + j + 2], md = col_list[start + j + 3];
    float4 va = *(const float4*)&xlin[(((size_t)(b << 12) + ma) << 8) + c4 * 4];
    float4 vb = *(const float4*)&xlin[(((size_t)(b << 12) + mb2) << 8) + c4 * 4];
    float4 vc = *(const float4*)&xlin[(((size_t)(b << 12) + mc) << 8) + c4 * 4];
    float4 vd = *(const float4*)&xlin[(((size_t)(b << 12) + md) << 8) + c4 * 4];
    acc.x += (va.x + vb.x) + (vc.x + vd.x);
    acc.y += (va.y + vb.y) + (vc.y + vd.y);
    acc.z += (va.z + vb.z) + (vc.z + vd.z);
    acc.w += (va.w + vb.w) + (vc.w + vd.w);
  }
  for (; j < deg; ++j) {
    int m = col_list[start + j];
    float4 v = *(const float4*)&xlin[(((size_t)(b << 12) + m) << 8) + c4 * 4];
    acc.x += v.x; acc.y += v.y; acc.z += v.z; acc.w += v.w;
  }
  float inv = 1.f / (float)deg;
  acc.x *= inv; acc.y *= inv; acc.z *= inv; acc.w *= inv;
  *(float4*)&yd[((size_t)be << 8) + c4 * 4] = acc;
}

// ---------------- K7: g[n,c] = (sum_{e in row(n)} Yd[e,c]) / Dv[n]; indices preloaded, masked full-24
__global__ __launch_bounds__(256) void k_out2(const float* __restrict__ yd,
                                              const int* __restrict__ row_idx,
                                              const int* __restrict__ row_cnt,
                                              float* __restrict__ outf) {
  const int b = blockIdx.x >> 8;
  const int nt = blockIdx.x & 255;
  const int le = threadIdx.x >> 6;
  const int c4 = threadIdx.x & 63;
  for (int ii = 0; ii < 4; ++ii) {
    int n = nt * 16 + le * 4 + ii;
    int row = (b << 12) + n;
    int cnt = row_cnt[row];
    int idx[24];
    const int4* ip = (const int4*)(row_idx + (size_t)row * KNN);
#pragma unroll
    for (int t = 0; t < 6; ++t) {
      int4 v = ip[t];
      idx[4 * t] = v.x; idx[4 * t + 1] = v.y; idx[4 * t + 2] = v.z; idx[4 * t + 3] = v.w;
    }
    float4 acc = make_float4(0.f, 0.f, 0.f, 0.f);
#pragma unroll
    for (int j = 0; j < 24; ++j) {
      float wgt = (j < cnt) ? 1.f : 0.f;
      float4 v = *(const float4*)&yd[(((size_t)(b << 12) + idx[j]) << 8) + c4 * 4];
      acc.x = fmaf(wgt, v.x, acc.x);
      acc.y = fmaf(wgt, v.y, acc.y);
      acc.z = fmaf(wgt, v.z, acc.z);
      acc.w = fmaf(wgt, v.w, acc.w);
    }
    float inv = 1.f / (float)cnt;
    acc.x *= inv; acc.y *= inv; acc.z *= inv; acc.w *= inv;
    *(float4*)&outf[((size_t)row << 8) + c4 * 4] = acc;
  }
}

// ---------------- K8: outf += x (residual, via LDS transpose); accumulate BN sums
__global__ __launch_bounds__(256) void k_res_bn(const float* __restrict__ x,
                                                float* __restrict__ outf,
                                                float* __restrict__ bn_sum,
                                                float* __restrict__ bn_sumsq) {
  __shared__ float xt[256 * 69];
  const int b = blockIdx.x >> 6;
  const int n0 = (blockIdx.x & 63) << 6;
  const int tid = threadIdx.x;
#pragma unroll 4
  for (int k = 0; k < 16; ++k) {
    int q = tid + 256 * k;
    int c = q >> 4, f = q & 15;
    float4 v = *(const float4*)&x[((size_t)(b * CD + c)) * NB + n0 + 4 * f];
    xt[c * 69 + 4 * f + 0] = v.x;
    xt[c * 69 + 4 * f + 1] = v.y;
    xt[c * 69 + 4 * f + 2] = v.z;
    xt[c * 69 + 4 * f + 3] = v.w;
  }
  __syncthreads();
  float s = 0.f, q = 0.f;
  const size_t rbase = ((size_t)((b << 12) + n0)) << 8;
#pragma unroll 4
  for (int i = 0; i < 64; ++i) {
    float v = outf[rbase + (size_t)i * 256 + tid] + xt[tid * 69 + i];
    outf[rbase + (size_t)i * 256 + tid] = v;
    s += v;
    q = fmaf(v, v, q);
  }
  atomicAdd(&bn_sum[tid], s);
  atomicAdd(&bn_sumsq[tid], q);
}

// ---------------- K9: BN scale/shift per channel
__global__ __launch_bounds__(256) void k_bn(const float* __restrict__ bn_sum,
                                            const float* __restrict__ bn_sumsq,
                                            const float* __restrict__ gamma,
                                            const float* __restrict__ beta,
                                            float* __restrict__ scale,
                                            float* __restrict__ shift) {
  const int c = threadIdx.x;
  const float inv = 1.f / 16384.f;
  float mean = bn_sum[c] * inv;
  float var = bn_sumsq[c] * inv - mean * mean;
  float sc = gamma[c] * rsqrtf(var + 1e-5f);
  scale[c] = sc;
  shift[c] = beta[c] - mean * sc;
}

// ---------------- K10: normalize + SiLU + transpose to [B,C,N]
__global__ __launch_bounds__(256) void k_write(const float* __restrict__ outf,
                                               const float* __restrict__ scale,
                                               const float* __restrict__ shift,
                                               float* __restrict__ out) {
  __shared__ float tile[64 * 257];
  __shared__ float sc[256], sh[256];
  const int b = blockIdx.x >> 6;
  const int n0 = (blockIdx.x & 63) << 6;
  const int tid = threadIdx.x;
  sc[tid] = scale[tid];
  sh[tid] = shift[tid];
  __syncthreads();
#pragma unroll 4
  for (int i = 0; i < 64; ++i) {
    int idx = tid + 256 * i;
    int n = idx >> 8, c = idx & 255;
    float v = outf[(((size_t)(b << 12) + n0 + n) << 8) + c];
    v = fmaf(v, sc[c], sh[c]);
    float w = v / (1.f + expf(-v));  // SiLU
    tile[n * 257 + c] = w;
  }
  __syncthreads();
  const int nl = tid & 63;
  const int cg = tid >> 6;
#pragma unroll 4
  for (int j = 0; j < 64; ++j) {
    int c = cg * 64 + j;
    out[((size_t)(b * CD + c)) * NB + n0 + nl] = tile[nl * 257 + c];
  }
}

extern "C" void kernel_launch(void* const* d_in, const int* in_sizes, int n_in,
                              void* d_out, int out_size, void* d_ws, size_t ws_size,
                              hipStream_t stream) {
  const float* x      = (const float*)d_in[0];
  const float* fc_w   = (const float*)d_in[1];
  const float* fc_b   = (const float*)d_in[2];
  const float* dist_w = (const float*)d_in[3];
  const float* gamma  = (const float*)d_in[4];
  const float* beta   = (const float*)d_in[5];
  float* out = (float*)d_out;
  char* ws = (char*)d_ws;

  const size_t OFF_EHL   = 0;                   // 4 MB (16384 rows x 256 B)
  const size_t OFF_XLIN  = (size_t)4 << 20;
  const size_t OFF_YD    = (size_t)20 << 20;
  const size_t OFF_OUTF  = (size_t)36 << 20;
  const size_t OFF_SQ    = (size_t)52 << 20;
  const size_t OFF_RIDX  = OFF_SQ + 65536;
  const size_t OFF_RCNT  = OFF_RIDX + 1572864;
  const size_t OFF_CCNT  = OFF_RCNT + 65536;
  const size_t OFF_CSTART = OFF_CCNT + 65536;
  const size_t OFF_CCUR  = OFF_CSTART + 65536;
  const size_t OFF_CLIST = OFF_CCUR + 65536;
  const size_t OFF_BNS   = OFF_CLIST + 1572864;
  const size_t OFF_BNQ   = OFF_BNS + 1024;
  const size_t OFF_SCALE = OFF_BNQ + 1024;
  const size_t OFF_SHIFT = OFF_SCALE + 1024;
  const size_t TOTAL = OFF_SHIFT + 1024;
  if (ws_size < TOTAL) return;

  unsigned* emb_hl = (unsigned*)(ws + OFF_EHL);
  float* xlin  = (float*)(ws + OFF_XLIN);
  float* yd    = (float*)(ws + OFF_YD);
  float* outf  = (float*)(ws + OFF_OUTF);
  float* sq    = (float*)(ws + OFF_SQ);
  int* row_idx = (int*)(ws + OFF_RIDX);
  int* row_cnt = (int*)(ws + OFF_RCNT);
  int* col_cnt = (int*)(ws + OFF_CCNT);
  int* col_start = (int*)(ws + OFF_CSTART);
  int* col_cursor = (int*)(ws + OFF_CCUR);
  int* col_list = (int*)(ws + OFF_CLIST);
  float* bn_sum = (float*)(ws + OFF_BNS);
  float* bn_sumsq = (float*)(ws + OFF_BNQ);
  float* scale = (float*)(ws + OFF_SCALE);
  float* shift = (float*)(ws + OFF_SHIFT);

  hipMemsetAsync(col_cnt, 0, 65536, stream);
  hipMemsetAsync(bn_sum, 0, 2048, stream);

  k_emb<<<256, 256, 0, stream>>>(x, dist_w, emb_hl, sq);
  k_xlin<<<256, 256, 0, stream>>>(x, fc_w, fc_b, xlin);
  k_dist<<<256, 512, 0, stream>>>(emb_hl, sq, row_idx, row_cnt, col_cnt);
  k_scan<<<1, 256, 0, stream>>>(col_cnt, col_start, col_cursor);
  k_fill<<<64, 256, 0, stream>>>(row_idx, row_cnt, col_cursor, col_list);
  k_yd<<<4096, 256, 0, stream>>>(xlin, col_cnt, col_start, col_list, yd);
  k_out2<<<1024, 256, 0, stream>>>(yd, row_idx, row_cnt, outf);
  k_res_bn<<<256, 256, 0, stream>>>(x, outf, bn_sum, bn_sumsq);
  k_bn<<<1, 256, 0, stream>>>(bn_sum, bn_sumsq, gamma, beta, scale, shift);
  k_write<<<256, 256, 0, stream>>>(outf, scale, shift, out);
}